// Round 7
// baseline (332.672 us; speedup 1.0000x reference)
//
#include <hip/hip_runtime.h>
#include <math.h>

#define N_TOK 1024
#define C_DIM 384
#define H_NUM 12
#define PCOLS 1024
#define Q0 0
#define K0 192
#define V0 384
#define QP0 576
#define KP0 720
#define VP0 864
#define ATT_W 240
#define COEF 0.11785113019775792f   // 0.5*sqrt(2/36)
#define ISD 0.25f
#define CC2 (COEF * ISD)            // 0.029462...

// ---------- pack 6 weight mats into Wall[384][1024] (cols 1008..1023 zero) ----------
__global__ __launch_bounds__(256) void k_pack(
    const float* __restrict__ Wq, const float* __restrict__ Wk, const float* __restrict__ Wv,
    const float* __restrict__ Wqp, const float* __restrict__ Wkp, const float* __restrict__ Wvp,
    float* __restrict__ Wall)
{
    int t = blockIdx.x * 256 + threadIdx.x;
    int k = t >> 8;
    int col = (t & 255) * 4;
    float4 v;
    if (col < 192)       v = *(const float4*)(Wq  + k * 192 + col);
    else if (col < 384)  v = *(const float4*)(Wk  + k * 192 + col - 192);
    else if (col < 576)  v = *(const float4*)(Wv  + k * 192 + col - 384);
    else if (col < 720)  v = *(const float4*)(Wqp + k * 144 + col - 576);
    else if (col < 864)  v = *(const float4*)(Wkp + k * 144 + col - 720);
    else if (col < 1008) v = *(const float4*)(Wvp + k * 144 + col - 864);
    else                 v = make_float4(0.f, 0.f, 0.f, 0.f);
    *(float4*)(Wall + k * PCOLS + col) = v;
}

// ---------- proj GEMM: P[1024][1024] = x[1024][384] @ Wall[384][1024] ----------
__global__ __launch_bounds__(256) void k_proj(
    const float* __restrict__ x, const float* __restrict__ Wall, float* __restrict__ P)
{
    __shared__ float xs[64][17];
    __shared__ float wsh[16][64];
    int tid = threadIdx.x;
    int i0 = blockIdx.x * 64, c0 = blockIdx.y * 64;
    int lr = tid >> 2, lk = (tid & 3) * 4;
    int wr = tid >> 4, wc = (tid & 15) * 4;
    int ty = tid >> 4, tx = tid & 15;

    float4 xa = *(const float4*)(x + (i0 + lr) * C_DIM + lk);
    float4 wa = *(const float4*)(Wall + wr * PCOLS + c0 + wc);
    float acc[4][4] = {};

    for (int it = 0; it < 24; ++it) {
        xs[lr][lk + 0] = xa.x; xs[lr][lk + 1] = xa.y;
        xs[lr][lk + 2] = xa.z; xs[lr][lk + 3] = xa.w;
        *(float4*)&wsh[wr][wc] = wa;
        __syncthreads();
        if (it < 23) {
            xa = *(const float4*)(x + (i0 + lr) * C_DIM + (it + 1) * 16 + lk);
            wa = *(const float4*)(Wall + ((it + 1) * 16 + wr) * PCOLS + c0 + wc);
        }
#pragma unroll
        for (int kk = 0; kk < 16; ++kk) {
            float4 b = *(float4*)&wsh[kk][tx * 4];
            float a0 = xs[ty * 4 + 0][kk];
            float a1 = xs[ty * 4 + 1][kk];
            float a2 = xs[ty * 4 + 2][kk];
            float a3 = xs[ty * 4 + 3][kk];
            acc[0][0] = fmaf(a0, b.x, acc[0][0]); acc[0][1] = fmaf(a0, b.y, acc[0][1]);
            acc[0][2] = fmaf(a0, b.z, acc[0][2]); acc[0][3] = fmaf(a0, b.w, acc[0][3]);
            acc[1][0] = fmaf(a1, b.x, acc[1][0]); acc[1][1] = fmaf(a1, b.y, acc[1][1]);
            acc[1][2] = fmaf(a1, b.z, acc[1][2]); acc[1][3] = fmaf(a1, b.w, acc[1][3]);
            acc[2][0] = fmaf(a2, b.x, acc[2][0]); acc[2][1] = fmaf(a2, b.y, acc[2][1]);
            acc[2][2] = fmaf(a2, b.z, acc[2][2]); acc[2][3] = fmaf(a2, b.w, acc[2][3]);
            acc[3][0] = fmaf(a3, b.x, acc[3][0]); acc[3][1] = fmaf(a3, b.y, acc[3][1]);
            acc[3][2] = fmaf(a3, b.z, acc[3][2]); acc[3][3] = fmaf(a3, b.w, acc[3][3]);
        }
        __syncthreads();
    }
#pragma unroll
    for (int r = 0; r < 4; ++r) {
        *(float4*)(P + (i0 + ty * 4 + r) * PCOLS + c0 + tx * 4) =
            make_float4(acc[r][0], acc[r][1], acc[r][2], acc[r][3]);
    }
}

// ---------- prep: build d-major Q'[h][29][1024], KV'[h][57][1024], qc[h][1024] ----------
// grid (8 nb, 12 h), 256 thr. Threads 0-127: K' col for token; 128-255: Q'+V'+qc.
__global__ __launch_bounds__(256) void k_prep(
    const float* __restrict__ P, const float* __restrict__ rot, const float* __restrict__ trans,
    float* __restrict__ KVg, float* __restrict__ Qg, float* __restrict__ qcg)
{
    __shared__ float kb[29 * 128];
    __shared__ float qb[29 * 128];
    __shared__ float vb[28 * 128];
    __shared__ float qcb[128];
    int h = blockIdx.y, nb = blockIdx.x;
    int tid = threadIdx.x;
    int nl = tid & 127, role = tid >> 7;
    int n = nb * 128 + nl;
    const float* R = rot + n * 9;
    float R00 = R[0], R01 = R[1], R02 = R[2];
    float R10 = R[3], R11 = R[4], R12 = R[5];
    float R20 = R[6], R21 = R[7], R22 = R[8];
    float t0 = trans[n * 3 + 0], t1 = trans[n * 3 + 1], t2 = trans[n * 3 + 2];

    if (role == 0) {
        const float* kr = P + n * PCOLS + K0 + h * 16;
#pragma unroll
        for (int d = 0; d < 16; ++d) kb[d * 128 + nl] = kr[d];
        const float* kp = P + n * PCOLS + KP0 + h * 12;
        float k2 = 0.f;
#pragma unroll
        for (int pt = 0; pt < 4; ++pt) {
            float p0 = kp[pt * 3 + 0], p1 = kp[pt * 3 + 1], p2 = kp[pt * 3 + 2];
            float g0 = R00 * p0 + R01 * p1 + R02 * p2 + t0;
            float g1 = R10 * p0 + R11 * p1 + R12 * p2 + t1;
            float g2 = R20 * p0 + R21 * p1 + R22 * p2 + t2;
            kb[(16 + pt * 3 + 0) * 128 + nl] = g0;
            kb[(16 + pt * 3 + 1) * 128 + nl] = g1;
            kb[(16 + pt * 3 + 2) * 128 + nl] = g2;
            k2 += g0 * g0 + g1 * g1 + g2 * g2;
        }
        kb[28 * 128 + nl] = -CC2 * k2;
    } else {
        const float* qr = P + n * PCOLS + Q0 + h * 16;
#pragma unroll
        for (int d = 0; d < 16; ++d) qb[d * 128 + nl] = qr[d] * ISD;
        const float* qp = P + n * PCOLS + QP0 + h * 12;
        float q2 = 0.f;
#pragma unroll
        for (int pt = 0; pt < 4; ++pt) {
            float p0 = qp[pt * 3 + 0], p1 = qp[pt * 3 + 1], p2 = qp[pt * 3 + 2];
            float g0 = R00 * p0 + R01 * p1 + R02 * p2 + t0;
            float g1 = R10 * p0 + R11 * p1 + R12 * p2 + t1;
            float g2 = R20 * p0 + R21 * p1 + R22 * p2 + t2;
            qb[(16 + pt * 3 + 0) * 128 + nl] = g0 * (2.f * CC2);
            qb[(16 + pt * 3 + 1) * 128 + nl] = g1 * (2.f * CC2);
            qb[(16 + pt * 3 + 2) * 128 + nl] = g2 * (2.f * CC2);
            q2 += g0 * g0 + g1 * g1 + g2 * g2;
        }
        qb[28 * 128 + nl] = 1.0f;
        qcb[nl] = fmaf(-CC2, q2, -4.0f);
        const float* vr = P + n * PCOLS + V0 + h * 16;
#pragma unroll
        for (int d = 0; d < 16; ++d) vb[d * 128 + nl] = vr[d];
        const float* vp = P + n * PCOLS + VP0 + h * 12;
#pragma unroll
        for (int pt = 0; pt < 4; ++pt) {
            float p0 = vp[pt * 3 + 0], p1 = vp[pt * 3 + 1], p2 = vp[pt * 3 + 2];
            vb[(16 + pt * 3 + 0) * 128 + nl] = R00 * p0 + R01 * p1 + R02 * p2 + t0;
            vb[(16 + pt * 3 + 1) * 128 + nl] = R10 * p0 + R11 * p1 + R12 * p2 + t1;
            vb[(16 + pt * 3 + 2) * 128 + nl] = R20 * p0 + R21 * p1 + R22 * p2 + t2;
        }
    }
    __syncthreads();

    for (int u = tid; u < 57 * 32; u += 256) {
        int d = u >> 5, c4 = u & 31;
        float4 v = (d < 29) ? *(float4*)&kb[d * 128 + c4 * 4]
                            : *(float4*)&vb[(d - 29) * 128 + c4 * 4];
        *(float4*)&KVg[(h * 57 + d) * 1024 + nb * 128 + c4 * 4] = v;
    }
    for (int u = tid; u < 29 * 32; u += 256) {
        int d = u >> 5, c4 = u & 31;
        *(float4*)&Qg[(h * 29 + d) * 1024 + nb * 128 + c4 * 4] = *(float4*)&qb[d * 128 + c4 * 4];
    }
    if (tid < 32) *(float4*)&qcg[h * 1024 + nb * 128 + tid * 4] = *(float4*)&qcb[tid * 4];
}

// ---------- attention as register-tiled GEMM ----------
// grid (16, 12, 2), 256 thr (16 ty x 16 tx). Thread tile: 4 queries x 8 keys.
// Block covers 64 queries x 512 keys (4 tiles of 128, double-buffered LDS).
__global__ __launch_bounds__(256, 2) void k_attn(
    const float* __restrict__ KVg, const float* __restrict__ Qg,
    const float* __restrict__ qcg, float* __restrict__ part)
{
    __shared__ float Qs[29 * 64];
    __shared__ float KV[2][57 * 128];
    int tid = threadIdx.x;
    int ty = tid >> 4, tx = tid & 15;
    int i0 = blockIdx.x * 64;
    int h = blockIdx.y;
    int jz0 = blockIdx.z * 512;
    const float* KVh = KVg + h * 57 * 1024;

    float4 rS[8];
#define ALOAD(T) do { int j0 = jz0 + (T) * 128;                                   \
    _Pragma("unroll")                                                             \
    for (int s_ = 0; s_ < 8; ++s_) { int idx = tid + s_ * 256;                    \
        if (idx < 1824) rS[s_] = *(const float4*)&KVh[(idx >> 5) * 1024 + j0 + (idx & 31) * 4]; } } while (0)
#define AWRITE(T) do { float* b_ = KV[(T) & 1];                                   \
    _Pragma("unroll")                                                             \
    for (int s_ = 0; s_ < 8; ++s_) { int idx = tid + s_ * 256;                    \
        if (idx < 1824) *(float4*)&b_[(idx >> 5) * 128 + (idx & 31) * 4] = rS[s_]; } } while (0)

    for (int u = tid; u < 29 * 16; u += 256) {
        int d = u >> 4, c4 = u & 15;
        *(float4*)&Qs[d * 64 + c4 * 4] = *(const float4*)&Qg[(h * 29 + d) * 1024 + i0 + c4 * 4];
    }
    float qc[4];
#pragma unroll
    for (int r = 0; r < 4; ++r) qc[r] = qcg[h * 1024 + i0 + ty * 4 + r];

    ALOAD(0); AWRITE(0);
    __syncthreads();

    float out[4][28] = {};
    float denom[4] = {};

    for (int t = 0; t < 4; ++t) {
        if (t < 3) ALOAD(t + 1);
        const float* Kb = KV[t & 1];
        const float* Vb = Kb + 29 * 128;

        float s[4][8];
#pragma unroll
        for (int r = 0; r < 4; ++r)
#pragma unroll
            for (int j = 0; j < 8; ++j) s[r][j] = 0.f;

#pragma unroll
        for (int d = 0; d < 29; ++d) {
            float4 qv = *(const float4*)&Qs[d * 64 + ty * 4];
            float4 k0 = *(const float4*)&Kb[d * 128 + tx * 8];
            float4 k1 = *(const float4*)&Kb[d * 128 + tx * 8 + 4];
            float qa[4] = {qv.x, qv.y, qv.z, qv.w};
            float ka[8] = {k0.x, k0.y, k0.z, k0.w, k1.x, k1.y, k1.z, k1.w};
#pragma unroll
            for (int r = 0; r < 4; ++r)
#pragma unroll
                for (int j = 0; j < 8; ++j) s[r][j] = fmaf(qa[r], ka[j], s[r][j]);
        }

        float p[4][8];
#pragma unroll
        for (int r = 0; r < 4; ++r) {
#pragma unroll
            for (int j = 0; j < 8; ++j) {
                p[r][j] = __expf(s[r][j] + qc[r]);
                denom[r] += p[r][j];
            }
        }

#pragma unroll
        for (int d = 0; d < 28; ++d) {
            float4 v0 = *(const float4*)&Vb[d * 128 + tx * 8];
            float4 v1 = *(const float4*)&Vb[d * 128 + tx * 8 + 4];
            float va[8] = {v0.x, v0.y, v0.z, v0.w, v1.x, v1.y, v1.z, v1.w};
#pragma unroll
            for (int r = 0; r < 4; ++r) {
                float acc = out[r][d];
#pragma unroll
                for (int j = 0; j < 8; ++j) acc = fmaf(p[r][j], va[j], acc);
                out[r][d] = acc;
            }
        }
        if (t < 3) AWRITE(t + 1);
        __syncthreads();
    }

    // butterfly reduce across the 16 tx lanes (lane bits 0..3)
#pragma unroll
    for (int m = 1; m <= 8; m <<= 1) {
#pragma unroll
        for (int r = 0; r < 4; ++r) {
#pragma unroll
            for (int d = 0; d < 28; ++d) out[r][d] += __shfl_xor(out[r][d], m, 64);
            denom[r] += __shfl_xor(denom[r], m, 64);
        }
    }
    if (tx == 0) {
#pragma unroll
        for (int r = 0; r < 4; ++r) {
#pragma unroll
            for (int d = 0; d < 28; ++d) Qs[d * 64 + ty * 4 + r] = out[r][d];
            Qs[28 * 64 + ty * 4 + r] = denom[r];
        }
    }
    __syncthreads();
    for (int u = tid; u < 29 * 64; u += 256) {
        part[((blockIdx.z * H_NUM + h) * 29 + (u >> 6)) * N_TOK + i0 + (u & 63)] = Qs[u];
    }
}

// ---------- combine partials, normalize, point-norm epilogue ----------
__global__ __launch_bounds__(256) void k_comb(
    const float* __restrict__ part, const float* __restrict__ rot,
    const float* __restrict__ trans, float* __restrict__ att)
{
    int t = blockIdx.x * 256 + threadIdx.x;
    int h = t >> 10, i = t & 1023;
    float v[29];
#pragma unroll
    for (int c = 0; c < 29; ++c) {
        v[c] = part[(h * 29 + c) * N_TOK + i] +
               part[((H_NUM + h) * 29 + c) * N_TOK + i];
    }
    float inv = 1.f / v[28];
    float* arow = att + i * ATT_W;
#pragma unroll
    for (int d = 0; d < 16; ++d) arow[h * 16 + d] = v[d] * inv;
    float t0 = trans[i * 3 + 0], t1 = trans[i * 3 + 1], t2v = trans[i * 3 + 2];
    const float* R = rot + i * 9;
#pragma unroll
    for (int p = 0; p < 4; ++p) {
        float c0 = v[16 + p * 3 + 0] * inv - t0;
        float c1 = v[16 + p * 3 + 1] * inv - t1;
        float c2 = v[16 + p * 3 + 2] * inv - t2v;
        float l0 = R[0] * c0 + R[3] * c1 + R[6] * c2;
        float l1 = R[1] * c0 + R[4] * c1 + R[7] * c2;
        float l2 = R[2] * c0 + R[5] * c1 + R[8] * c2;
        arow[192 + h * 4 + p] = sqrtf(l0 * l0 + l1 * l1 + l2 * l2);
    }
}

// ---------- out GEMM: out[1024][384] = att[1024][240] @ Wout[240][384] + bout ----------
__global__ __launch_bounds__(256) void k_out(
    const float* __restrict__ att, const float* __restrict__ Wout,
    const float* __restrict__ bout, float* __restrict__ out)
{
    __shared__ float xs[64][17];
    __shared__ float wsh[16][64];
    int tid = threadIdx.x;
    int i0 = blockIdx.x * 64, c0 = blockIdx.y * 64;
    int lr = tid >> 2, lk = (tid & 3) * 4;
    int wr = tid >> 4, wc = (tid & 15) * 4;
    int ty = tid >> 4, tx = tid & 15;

    float4 xa = *(const float4*)(att + (i0 + lr) * ATT_W + lk);
    float4 wa = *(const float4*)(Wout + wr * C_DIM + c0 + wc);
    float acc[4][4] = {};

    for (int it = 0; it < 15; ++it) {
        xs[lr][lk + 0] = xa.x; xs[lr][lk + 1] = xa.y;
        xs[lr][lk + 2] = xa.z; xs[lr][lk + 3] = xa.w;
        *(float4*)&wsh[wr][wc] = wa;
        __syncthreads();
        if (it < 14) {
            xa = *(const float4*)(att + (i0 + lr) * ATT_W + (it + 1) * 16 + lk);
            wa = *(const float4*)(Wout + ((it + 1) * 16 + wr) * C_DIM + c0 + wc);
        }
#pragma unroll
        for (int kk = 0; kk < 16; ++kk) {
            float4 b = *(float4*)&wsh[kk][tx * 4];
            float a0 = xs[ty * 4 + 0][kk];
            float a1 = xs[ty * 4 + 1][kk];
            float a2 = xs[ty * 4 + 2][kk];
            float a3 = xs[ty * 4 + 3][kk];
            acc[0][0] = fmaf(a0, b.x, acc[0][0]); acc[0][1] = fmaf(a0, b.y, acc[0][1]);
            acc[0][2] = fmaf(a0, b.z, acc[0][2]); acc[0][3] = fmaf(a0, b.w, acc[0][3]);
            acc[1][0] = fmaf(a1, b.x, acc[1][0]); acc[1][1] = fmaf(a1, b.y, acc[1][1]);
            acc[1][2] = fmaf(a1, b.z, acc[1][2]); acc[1][3] = fmaf(a1, b.w, acc[1][3]);
            acc[2][0] = fmaf(a2, b.x, acc[2][0]); acc[2][1] = fmaf(a2, b.y, acc[2][1]);
            acc[2][2] = fmaf(a2, b.z, acc[2][2]); acc[2][3] = fmaf(a2, b.w, acc[2][3]);
            acc[3][0] = fmaf(a3, b.x, acc[3][0]); acc[3][1] = fmaf(a3, b.y, acc[3][1]);
            acc[3][2] = fmaf(a3, b.z, acc[3][2]); acc[3][3] = fmaf(a3, b.w, acc[3][3]);
        }
        __syncthreads();
    }
    float4 bb = *(const float4*)(bout + c0 + tx * 4);
#pragma unroll
    for (int r = 0; r < 4; ++r) {
        *(float4*)(out + (i0 + ty * 4 + r) * C_DIM + c0 + tx * 4) =
            make_float4(acc[r][0] + bb.x, acc[r][1] + bb.y, acc[r][2] + bb.z, acc[r][3] + bb.w);
    }
}

extern "C" void kernel_launch(void* const* d_in, const int* in_sizes, int n_in,
                              void* d_out, int out_size, void* d_ws, size_t ws_size,
                              hipStream_t stream) {
    const float* x     = (const float*)d_in[0];
    const float* rot   = (const float*)d_in[1];
    const float* trans = (const float*)d_in[2];
    const float* Wq    = (const float*)d_in[3];
    const float* Wk    = (const float*)d_in[4];
    const float* Wv    = (const float*)d_in[5];
    const float* Wqp   = (const float*)d_in[6];
    const float* Wkp   = (const float*)d_in[7];
    const float* Wvp   = (const float*)d_in[8];
    const float* Wout  = (const float*)d_in[9];
    const float* bout  = (const float*)d_in[10];
    float* out = (float*)d_out;

    float* ws = (float*)d_ws;
    float* Wall = ws;                          // 384*1024
    float* P    = Wall + C_DIM * PCOLS;        // 1024*1024
    float* KVg  = P    + N_TOK * PCOLS;        // 12*57*1024
    float* Qg   = KVg  + H_NUM * 57 * 1024;    // 12*29*1024
    float* qcg  = Qg   + H_NUM * 29 * 1024;    // 12*1024
    float* part = P;                           // alias: P dead after k_prep (2*12*29*1024 <= 1024*1024)
    float* att  = Qg;                          // alias: Qg dead after k_attn (1024*240 <= 12*29*1024)

    k_pack<<<384, 256, 0, stream>>>(Wq, Wk, Wv, Wqp, Wkp, Wvp, Wall);
    k_proj<<<dim3(16, 16), 256, 0, stream>>>(x, Wall, P);
    k_prep<<<dim3(8, 12), 256, 0, stream>>>(P, rot, trans, KVg, Qg, qcg);
    k_attn<<<dim3(16, 12, 2), 256, 0, stream>>>(KVg, Qg, qcg, part);
    k_comb<<<48, 256, 0, stream>>>(part, rot, trans, att);
    k_out<<<dim3(16, 6), 256, 0, stream>>>(att, Wout, bout, out);
}

// Round 8
// 137.809 us; speedup vs baseline: 2.4140x; 2.4140x over previous
//
#include <hip/hip_runtime.h>
#include <math.h>

#define N_TOK 1024
#define C_DIM 384
#define H_NUM 12
#define PCOLS 1024
#define Q0 0
#define K0 192
#define V0 384
#define QP0 576
#define KP0 720
#define VP0 864
#define ATT_W 240
#define COEF 0.11785113019775792f   // 0.5*sqrt(2/36)
#define ISD 0.25f
#define CC2 (COEF * ISD)            // 0.029462...

// ---------- pack 6 weight mats into Wall[384][1024] (cols 1008..1023 zero) ----------
__global__ __launch_bounds__(256) void k_pack(
    const float* __restrict__ Wq, const float* __restrict__ Wk, const float* __restrict__ Wv,
    const float* __restrict__ Wqp, const float* __restrict__ Wkp, const float* __restrict__ Wvp,
    float* __restrict__ Wall)
{
    int t = blockIdx.x * 256 + threadIdx.x;
    int k = t >> 8;
    int col = (t & 255) * 4;
    float4 v;
    if (col < 192)       v = *(const float4*)(Wq  + k * 192 + col);
    else if (col < 384)  v = *(const float4*)(Wk  + k * 192 + col - 192);
    else if (col < 576)  v = *(const float4*)(Wv  + k * 192 + col - 384);
    else if (col < 720)  v = *(const float4*)(Wqp + k * 144 + col - 576);
    else if (col < 864)  v = *(const float4*)(Wkp + k * 144 + col - 720);
    else if (col < 1008) v = *(const float4*)(Wvp + k * 144 + col - 864);
    else                 v = make_float4(0.f, 0.f, 0.f, 0.f);
    *(float4*)(Wall + k * PCOLS + col) = v;
}

// ---------- proj GEMM: P[1024][1024] = x[1024][384] @ Wall[384][1024] ----------
__global__ __launch_bounds__(256) void k_proj(
    const float* __restrict__ x, const float* __restrict__ Wall, float* __restrict__ P)
{
    __shared__ float xs[64][17];
    __shared__ float wsh[16][64];
    int tid = threadIdx.x;
    int i0 = blockIdx.x * 64, c0 = blockIdx.y * 64;
    int lr = tid >> 2, lk = (tid & 3) * 4;
    int wr = tid >> 4, wc = (tid & 15) * 4;
    int ty = tid >> 4, tx = tid & 15;

    float4 xa = *(const float4*)(x + (i0 + lr) * C_DIM + lk);
    float4 wa = *(const float4*)(Wall + wr * PCOLS + c0 + wc);
    float acc[4][4] = {};

    for (int it = 0; it < 24; ++it) {
        xs[lr][lk + 0] = xa.x; xs[lr][lk + 1] = xa.y;
        xs[lr][lk + 2] = xa.z; xs[lr][lk + 3] = xa.w;
        *(float4*)&wsh[wr][wc] = wa;
        __syncthreads();
        if (it < 23) {
            xa = *(const float4*)(x + (i0 + lr) * C_DIM + (it + 1) * 16 + lk);
            wa = *(const float4*)(Wall + ((it + 1) * 16 + wr) * PCOLS + c0 + wc);
        }
#pragma unroll
        for (int kk = 0; kk < 16; ++kk) {
            float4 b = *(float4*)&wsh[kk][tx * 4];
            float a0 = xs[ty * 4 + 0][kk];
            float a1 = xs[ty * 4 + 1][kk];
            float a2 = xs[ty * 4 + 2][kk];
            float a3 = xs[ty * 4 + 3][kk];
            acc[0][0] = fmaf(a0, b.x, acc[0][0]); acc[0][1] = fmaf(a0, b.y, acc[0][1]);
            acc[0][2] = fmaf(a0, b.z, acc[0][2]); acc[0][3] = fmaf(a0, b.w, acc[0][3]);
            acc[1][0] = fmaf(a1, b.x, acc[1][0]); acc[1][1] = fmaf(a1, b.y, acc[1][1]);
            acc[1][2] = fmaf(a1, b.z, acc[1][2]); acc[1][3] = fmaf(a1, b.w, acc[1][3]);
            acc[2][0] = fmaf(a2, b.x, acc[2][0]); acc[2][1] = fmaf(a2, b.y, acc[2][1]);
            acc[2][2] = fmaf(a2, b.z, acc[2][2]); acc[2][3] = fmaf(a2, b.w, acc[2][3]);
            acc[3][0] = fmaf(a3, b.x, acc[3][0]); acc[3][1] = fmaf(a3, b.y, acc[3][1]);
            acc[3][2] = fmaf(a3, b.z, acc[3][2]); acc[3][3] = fmaf(a3, b.w, acc[3][3]);
        }
        __syncthreads();
    }
#pragma unroll
    for (int r = 0; r < 4; ++r) {
        *(float4*)(P + (i0 + ty * 4 + r) * PCOLS + c0 + tx * 4) =
            make_float4(acc[r][0], acc[r][1], acc[r][2], acc[r][3]);
    }
}

// ---------- prep: build d-major Q'[h][29][1024], KV'[h][57][1024], qc[h][1024] ----------
__global__ __launch_bounds__(256) void k_prep(
    const float* __restrict__ P, const float* __restrict__ rot, const float* __restrict__ trans,
    float* __restrict__ KVg, float* __restrict__ Qg, float* __restrict__ qcg)
{
    __shared__ float kb[29 * 128];
    __shared__ float qb[29 * 128];
    __shared__ float vb[28 * 128];
    __shared__ float qcb[128];
    int h = blockIdx.y, nb = blockIdx.x;
    int tid = threadIdx.x;
    int nl = tid & 127, role = tid >> 7;
    int n = nb * 128 + nl;
    const float* R = rot + n * 9;
    float R00 = R[0], R01 = R[1], R02 = R[2];
    float R10 = R[3], R11 = R[4], R12 = R[5];
    float R20 = R[6], R21 = R[7], R22 = R[8];
    float t0 = trans[n * 3 + 0], t1 = trans[n * 3 + 1], t2 = trans[n * 3 + 2];

    if (role == 0) {
        const float* kr = P + n * PCOLS + K0 + h * 16;
#pragma unroll
        for (int d = 0; d < 16; ++d) kb[d * 128 + nl] = kr[d];
        const float* kp = P + n * PCOLS + KP0 + h * 12;
        float k2 = 0.f;
#pragma unroll
        for (int pt = 0; pt < 4; ++pt) {
            float p0 = kp[pt * 3 + 0], p1 = kp[pt * 3 + 1], p2 = kp[pt * 3 + 2];
            float g0 = R00 * p0 + R01 * p1 + R02 * p2 + t0;
            float g1 = R10 * p0 + R11 * p1 + R12 * p2 + t1;
            float g2 = R20 * p0 + R21 * p1 + R22 * p2 + t2;
            kb[(16 + pt * 3 + 0) * 128 + nl] = g0;
            kb[(16 + pt * 3 + 1) * 128 + nl] = g1;
            kb[(16 + pt * 3 + 2) * 128 + nl] = g2;
            k2 += g0 * g0 + g1 * g1 + g2 * g2;
        }
        kb[28 * 128 + nl] = -CC2 * k2;
    } else {
        const float* qr = P + n * PCOLS + Q0 + h * 16;
#pragma unroll
        for (int d = 0; d < 16; ++d) qb[d * 128 + nl] = qr[d] * ISD;
        const float* qp = P + n * PCOLS + QP0 + h * 12;
        float q2 = 0.f;
#pragma unroll
        for (int pt = 0; pt < 4; ++pt) {
            float p0 = qp[pt * 3 + 0], p1 = qp[pt * 3 + 1], p2 = qp[pt * 3 + 2];
            float g0 = R00 * p0 + R01 * p1 + R02 * p2 + t0;
            float g1 = R10 * p0 + R11 * p1 + R12 * p2 + t1;
            float g2 = R20 * p0 + R21 * p1 + R22 * p2 + t2;
            qb[(16 + pt * 3 + 0) * 128 + nl] = g0 * (2.f * CC2);
            qb[(16 + pt * 3 + 1) * 128 + nl] = g1 * (2.f * CC2);
            qb[(16 + pt * 3 + 2) * 128 + nl] = g2 * (2.f * CC2);
            q2 += g0 * g0 + g1 * g1 + g2 * g2;
        }
        qb[28 * 128 + nl] = 1.0f;
        qcb[nl] = fmaf(-CC2, q2, -4.0f);
        const float* vr = P + n * PCOLS + V0 + h * 16;
#pragma unroll
        for (int d = 0; d < 16; ++d) vb[d * 128 + nl] = vr[d];
        const float* vp = P + n * PCOLS + VP0 + h * 12;
#pragma unroll
        for (int pt = 0; pt < 4; ++pt) {
            float p0 = vp[pt * 3 + 0], p1 = vp[pt * 3 + 1], p2 = vp[pt * 3 + 2];
            vb[(16 + pt * 3 + 0) * 128 + nl] = R00 * p0 + R01 * p1 + R02 * p2 + t0;
            vb[(16 + pt * 3 + 1) * 128 + nl] = R10 * p0 + R11 * p1 + R12 * p2 + t1;
            vb[(16 + pt * 3 + 2) * 128 + nl] = R20 * p0 + R21 * p1 + R22 * p2 + t2;
        }
    }
    __syncthreads();

    for (int u = tid; u < 57 * 32; u += 256) {
        int d = u >> 5, c4 = u & 31;
        float4 v = (d < 29) ? *(float4*)&kb[d * 128 + c4 * 4]
                            : *(float4*)&vb[(d - 29) * 128 + c4 * 4];
        *(float4*)&KVg[(h * 57 + d) * 1024 + nb * 128 + c4 * 4] = v;
    }
    for (int u = tid; u < 29 * 32; u += 256) {
        int d = u >> 5, c4 = u & 31;
        *(float4*)&Qg[(h * 29 + d) * 1024 + nb * 128 + c4 * 4] = *(float4*)&qb[d * 128 + c4 * 4];
    }
    if (tid < 32) *(float4*)&qcg[h * 1024 + nb * 128 + tid * 4] = *(float4*)&qcb[tid * 4];
}

// ---------- attention as register-tiled GEMM ----------
// grid (16, 12, 2), 256 thr (16 ty x 16 tx). Thread tile: 4 queries x 4 keys.
// Block: 64 queries x 512 keys (8 tiles of 64, double-buffered LDS ~36.6 KB).
__global__ __launch_bounds__(256, 1) void k_attn(
    const float* __restrict__ KVg, const float* __restrict__ Qg,
    const float* __restrict__ qcg, float* __restrict__ part)
{
    __shared__ float Qs[29 * 64];
    __shared__ float KV[2][57 * 64];
    int tid = threadIdx.x;
    int ty = tid >> 4, tx = tid & 15;
    int i0 = blockIdx.x * 64;
    int h = blockIdx.y;
    int jz0 = blockIdx.z * 512;
    const float* KVh = KVg + h * 57 * 1024;

    float4 rS[4];
#define ALOAD(T) do { int j0 = jz0 + (T) * 64;                                   \
    _Pragma("unroll")                                                            \
    for (int s_ = 0; s_ < 4; ++s_) { int idx = tid + s_ * 256;                   \
        if (idx < 912) rS[s_] = *(const float4*)&KVh[(idx >> 4) * 1024 + j0 + (idx & 15) * 4]; } } while (0)
#define AWRITE(T) do { float* b_ = KV[(T) & 1];                                  \
    _Pragma("unroll")                                                            \
    for (int s_ = 0; s_ < 4; ++s_) { int idx = tid + s_ * 256;                   \
        if (idx < 912) *(float4*)&b_[(idx >> 4) * 64 + (idx & 15) * 4] = rS[s_]; } } while (0)

    for (int u = tid; u < 29 * 16; u += 256) {
        int d = u >> 4, c4 = u & 15;
        *(float4*)&Qs[d * 64 + c4 * 4] = *(const float4*)&Qg[(h * 29 + d) * 1024 + i0 + c4 * 4];
    }
    float qc[4];
#pragma unroll
    for (int r = 0; r < 4; ++r) qc[r] = qcg[h * 1024 + i0 + ty * 4 + r];

    ALOAD(0); AWRITE(0);
    __syncthreads();

    float out[4][28] = {};
    float denom[4] = {};

    for (int t = 0; t < 8; ++t) {
        if (t < 7) ALOAD(t + 1);
        const float* Kb = KV[t & 1];
        const float* Vb = Kb + 29 * 64;

        float s[4][4] = {};
#pragma unroll
        for (int d = 0; d < 29; ++d) {
            float4 qv = *(const float4*)&Qs[d * 64 + ty * 4];
            float4 kv = *(const float4*)&Kb[d * 64 + tx * 4];
            float qa[4] = {qv.x, qv.y, qv.z, qv.w};
            float ka[4] = {kv.x, kv.y, kv.z, kv.w};
#pragma unroll
            for (int r = 0; r < 4; ++r)
#pragma unroll
                for (int j = 0; j < 4; ++j) s[r][j] = fmaf(qa[r], ka[j], s[r][j]);
        }

        float p[4][4];
#pragma unroll
        for (int r = 0; r < 4; ++r) {
#pragma unroll
            for (int j = 0; j < 4; ++j) {
                p[r][j] = __expf(s[r][j] + qc[r]);
                denom[r] += p[r][j];
            }
        }

#pragma unroll
        for (int d = 0; d < 28; ++d) {
            float4 vv = *(const float4*)&Vb[d * 64 + tx * 4];
            float va[4] = {vv.x, vv.y, vv.z, vv.w};
#pragma unroll
            for (int r = 0; r < 4; ++r) {
                float acc = out[r][d];
#pragma unroll
                for (int j = 0; j < 4; ++j) acc = fmaf(p[r][j], va[j], acc);
                out[r][d] = acc;
            }
        }
        if (t < 7) AWRITE(t + 1);
        __syncthreads();
    }

    // butterfly reduce across the 16 tx lanes (lane bits 0..3)
#pragma unroll
    for (int m = 1; m <= 8; m <<= 1) {
#pragma unroll
        for (int r = 0; r < 4; ++r) {
#pragma unroll
            for (int d = 0; d < 28; ++d) out[r][d] += __shfl_xor(out[r][d], m, 64);
            denom[r] += __shfl_xor(denom[r], m, 64);
        }
    }
    if (tx == 0) {
#pragma unroll
        for (int r = 0; r < 4; ++r) {
#pragma unroll
            for (int d = 0; d < 28; ++d) Qs[d * 64 + ty * 4 + r] = out[r][d];
            Qs[28 * 64 + ty * 4 + r] = denom[r];
        }
    }
    __syncthreads();
    for (int u = tid; u < 29 * 64; u += 256) {
        part[((blockIdx.z * H_NUM + h) * 29 + (u >> 6)) * N_TOK + i0 + (u & 63)] = Qs[u];
    }
}

// ---------- combine partials, normalize, point-norm epilogue ----------
__global__ __launch_bounds__(256) void k_comb(
    const float* __restrict__ part, const float* __restrict__ rot,
    const float* __restrict__ trans, float* __restrict__ att)
{
    int t = blockIdx.x * 256 + threadIdx.x;
    int h = t >> 10, i = t & 1023;
    float v[29];
#pragma unroll
    for (int c = 0; c < 29; ++c) {
        v[c] = part[(h * 29 + c) * N_TOK + i] +
               part[((H_NUM + h) * 29 + c) * N_TOK + i];
    }
    float inv = 1.f / v[28];
    float* arow = att + i * ATT_W;
#pragma unroll
    for (int d = 0; d < 16; ++d) arow[h * 16 + d] = v[d] * inv;
    float t0 = trans[i * 3 + 0], t1 = trans[i * 3 + 1], t2v = trans[i * 3 + 2];
    const float* R = rot + i * 9;
#pragma unroll
    for (int p = 0; p < 4; ++p) {
        float c0 = v[16 + p * 3 + 0] * inv - t0;
        float c1 = v[16 + p * 3 + 1] * inv - t1;
        float c2 = v[16 + p * 3 + 2] * inv - t2v;
        float l0 = R[0] * c0 + R[3] * c1 + R[6] * c2;
        float l1 = R[1] * c0 + R[4] * c1 + R[7] * c2;
        float l2 = R[2] * c0 + R[5] * c1 + R[8] * c2;
        arow[192 + h * 4 + p] = sqrtf(l0 * l0 + l1 * l1 + l2 * l2);
    }
}

// ---------- out GEMM: out[1024][384] = att[1024][240] @ Wout[240][384] + bout ----------
__global__ __launch_bounds__(256) void k_out(
    const float* __restrict__ att, const float* __restrict__ Wout,
    const float* __restrict__ bout, float* __restrict__ out)
{
    __shared__ float xs[64][17];
    __shared__ float wsh[16][64];
    int tid = threadIdx.x;
    int i0 = blockIdx.x * 64, c0 = blockIdx.y * 64;
    int lr = tid >> 2, lk = (tid & 3) * 4;
    int wr = tid >> 4, wc = (tid & 15) * 4;
    int ty = tid >> 4, tx = tid & 15;

    float4 xa = *(const float4*)(att + (i0 + lr) * ATT_W + lk);
    float4 wa = *(const float4*)(Wout + wr * C_DIM + c0 + wc);
    float acc[4][4] = {};

    for (int it = 0; it < 15; ++it) {
        xs[lr][lk + 0] = xa.x; xs[lr][lk + 1] = xa.y;
        xs[lr][lk + 2] = xa.z; xs[lr][lk + 3] = xa.w;
        *(float4*)&wsh[wr][wc] = wa;
        __syncthreads();
        if (it < 14) {
            xa = *(const float4*)(att + (i0 + lr) * ATT_W + (it + 1) * 16 + lk);
            wa = *(const float4*)(Wout + ((it + 1) * 16 + wr) * C_DIM + c0 + wc);
        }
#pragma unroll
        for (int kk = 0; kk < 16; ++kk) {
            float4 b = *(float4*)&wsh[kk][tx * 4];
            float a0 = xs[ty * 4 + 0][kk];
            float a1 = xs[ty * 4 + 1][kk];
            float a2 = xs[ty * 4 + 2][kk];
            float a3 = xs[ty * 4 + 3][kk];
            acc[0][0] = fmaf(a0, b.x, acc[0][0]); acc[0][1] = fmaf(a0, b.y, acc[0][1]);
            acc[0][2] = fmaf(a0, b.z, acc[0][2]); acc[0][3] = fmaf(a0, b.w, acc[0][3]);
            acc[1][0] = fmaf(a1, b.x, acc[1][0]); acc[1][1] = fmaf(a1, b.y, acc[1][1]);
            acc[1][2] = fmaf(a1, b.z, acc[1][2]); acc[1][3] = fmaf(a1, b.w, acc[1][3]);
            acc[2][0] = fmaf(a2, b.x, acc[2][0]); acc[2][1] = fmaf(a2, b.y, acc[2][1]);
            acc[2][2] = fmaf(a2, b.z, acc[2][2]); acc[2][3] = fmaf(a2, b.w, acc[2][3]);
            acc[3][0] = fmaf(a3, b.x, acc[3][0]); acc[3][1] = fmaf(a3, b.y, acc[3][1]);
            acc[3][2] = fmaf(a3, b.z, acc[3][2]); acc[3][3] = fmaf(a3, b.w, acc[3][3]);
        }
        __syncthreads();
    }
    float4 bb = *(const float4*)(bout + c0 + tx * 4);
#pragma unroll
    for (int r = 0; r < 4; ++r) {
        *(float4*)(out + (i0 + ty * 4 + r) * C_DIM + c0 + tx * 4) =
            make_float4(acc[r][0] + bb.x, acc[r][1] + bb.y, acc[r][2] + bb.z, acc[r][3] + bb.w);
    }
}

extern "C" void kernel_launch(void* const* d_in, const int* in_sizes, int n_in,
                              void* d_out, int out_size, void* d_ws, size_t ws_size,
                              hipStream_t stream) {
    const float* x     = (const float*)d_in[0];
    const float* rot   = (const float*)d_in[1];
    const float* trans = (const float*)d_in[2];
    const float* Wq    = (const float*)d_in[3];
    const float* Wk    = (const float*)d_in[4];
    const float* Wv    = (const float*)d_in[5];
    const float* Wqp   = (const float*)d_in[6];
    const float* Wkp   = (const float*)d_in[7];
    const float* Wvp   = (const float*)d_in[8];
    const float* Wout  = (const float*)d_in[9];
    const float* bout  = (const float*)d_in[10];
    float* out = (float*)d_out;

    float* ws = (float*)d_ws;
    float* Wall = ws;                          // 384*1024
    float* P    = Wall + C_DIM * PCOLS;        // 1024*1024
    float* KVg  = P    + N_TOK * PCOLS;        // 12*57*1024
    float* Qg   = KVg  + H_NUM * 57 * 1024;    // 12*29*1024
    float* qcg  = Qg   + H_NUM * 29 * 1024;    // 12*1024
    float* part = P;                           // alias: P dead after k_prep
    float* att  = Qg;                          // alias: Qg dead after k_attn

    k_pack<<<384, 256, 0, stream>>>(Wq, Wk, Wv, Wqp, Wkp, Wvp, Wall);
    k_proj<<<dim3(16, 16), 256, 0, stream>>>(x, Wall, P);
    k_prep<<<dim3(8, 12), 256, 0, stream>>>(P, rot, trans, KVg, Qg, qcg);
    k_attn<<<dim3(16, 12, 2), 256, 0, stream>>>(KVg, Qg, qcg, part);
    k_comb<<<48, 256, 0, stream>>>(part, rot, trans, att);
    k_out<<<dim3(16, 6), 256, 0, stream>>>(att, Wout, bout, out);
}

// Round 9
// 109.209 us; speedup vs baseline: 3.0462x; 1.2619x over previous
//
#include <hip/hip_runtime.h>
#include <math.h>

#define N_TOK 1024
#define C_DIM 384
#define H_NUM 12
#define PCOLS 1024
#define Q0 0
#define K0 192
#define V0 384
#define QP0 576
#define KP0 720
#define VP0 864
#define ATT_W 240
#define COEF 0.11785113019775792f   // 0.5*sqrt(2/36)
#define ISD 0.25f
#define CC2 (COEF * ISD)            // 0.029462...
#define KV_ROWS 60                  // 29 K' + 28 V' + 3 pad (DMA tiles by 4 rows)
#define NZ 4

// ---------- pack 6 weight mats into Wall[384][1024] (cols 1008..1023 zero) ----------
__global__ __launch_bounds__(256) void k_pack(
    const float* __restrict__ Wq, const float* __restrict__ Wk, const float* __restrict__ Wv,
    const float* __restrict__ Wqp, const float* __restrict__ Wkp, const float* __restrict__ Wvp,
    float* __restrict__ Wall)
{
    int t = blockIdx.x * 256 + threadIdx.x;
    int k = t >> 8;
    int col = (t & 255) * 4;
    float4 v;
    if (col < 192)       v = *(const float4*)(Wq  + k * 192 + col);
    else if (col < 384)  v = *(const float4*)(Wk  + k * 192 + col - 192);
    else if (col < 576)  v = *(const float4*)(Wv  + k * 192 + col - 384);
    else if (col < 720)  v = *(const float4*)(Wqp + k * 144 + col - 576);
    else if (col < 864)  v = *(const float4*)(Wkp + k * 144 + col - 720);
    else if (col < 1008) v = *(const float4*)(Wvp + k * 144 + col - 864);
    else                 v = make_float4(0.f, 0.f, 0.f, 0.f);
    *(float4*)(Wall + k * PCOLS + col) = v;
}

// ---------- proj GEMM: P[1024][1024] = x[1024][384] @ Wall[384][1024] ----------
__global__ __launch_bounds__(256) void k_proj(
    const float* __restrict__ x, const float* __restrict__ Wall, float* __restrict__ P)
{
    __shared__ float xs[64][17];
    __shared__ float wsh[16][64];
    int tid = threadIdx.x;
    int i0 = blockIdx.x * 64, c0 = blockIdx.y * 64;
    int lr = tid >> 2, lk = (tid & 3) * 4;
    int wr = tid >> 4, wc = (tid & 15) * 4;
    int ty = tid >> 4, tx = tid & 15;

    float4 xa = *(const float4*)(x + (i0 + lr) * C_DIM + lk);
    float4 wa = *(const float4*)(Wall + wr * PCOLS + c0 + wc);
    float acc[4][4] = {};

    for (int it = 0; it < 24; ++it) {
        xs[lr][lk + 0] = xa.x; xs[lr][lk + 1] = xa.y;
        xs[lr][lk + 2] = xa.z; xs[lr][lk + 3] = xa.w;
        *(float4*)&wsh[wr][wc] = wa;
        __syncthreads();
        if (it < 23) {
            xa = *(const float4*)(x + (i0 + lr) * C_DIM + (it + 1) * 16 + lk);
            wa = *(const float4*)(Wall + ((it + 1) * 16 + wr) * PCOLS + c0 + wc);
        }
#pragma unroll
        for (int kk = 0; kk < 16; ++kk) {
            float4 b = *(float4*)&wsh[kk][tx * 4];
            float a0 = xs[ty * 4 + 0][kk];
            float a1 = xs[ty * 4 + 1][kk];
            float a2 = xs[ty * 4 + 2][kk];
            float a3 = xs[ty * 4 + 3][kk];
            acc[0][0] = fmaf(a0, b.x, acc[0][0]); acc[0][1] = fmaf(a0, b.y, acc[0][1]);
            acc[0][2] = fmaf(a0, b.z, acc[0][2]); acc[0][3] = fmaf(a0, b.w, acc[0][3]);
            acc[1][0] = fmaf(a1, b.x, acc[1][0]); acc[1][1] = fmaf(a1, b.y, acc[1][1]);
            acc[1][2] = fmaf(a1, b.z, acc[1][2]); acc[1][3] = fmaf(a1, b.w, acc[1][3]);
            acc[2][0] = fmaf(a2, b.x, acc[2][0]); acc[2][1] = fmaf(a2, b.y, acc[2][1]);
            acc[2][2] = fmaf(a2, b.z, acc[2][2]); acc[2][3] = fmaf(a2, b.w, acc[2][3]);
            acc[3][0] = fmaf(a3, b.x, acc[3][0]); acc[3][1] = fmaf(a3, b.y, acc[3][1]);
            acc[3][2] = fmaf(a3, b.z, acc[3][2]); acc[3][3] = fmaf(a3, b.w, acc[3][3]);
        }
        __syncthreads();
    }
#pragma unroll
    for (int r = 0; r < 4; ++r) {
        *(float4*)(P + (i0 + ty * 4 + r) * PCOLS + c0 + tx * 4) =
            make_float4(acc[r][0], acc[r][1], acc[r][2], acc[r][3]);
    }
}

// ---------- prep: build d-major Q'[h][29][1024], KV'[h][60][1024], qc[h][1024] ----------
__global__ __launch_bounds__(256) void k_prep(
    const float* __restrict__ P, const float* __restrict__ rot, const float* __restrict__ trans,
    float* __restrict__ KVg, float* __restrict__ Qg, float* __restrict__ qcg)
{
    __shared__ float kb[29 * 128];
    __shared__ float qb[29 * 128];
    __shared__ float vb[28 * 128];
    __shared__ float qcb[128];
    int h = blockIdx.y, nb = blockIdx.x;
    int tid = threadIdx.x;
    int nl = tid & 127, role = tid >> 7;
    int n = nb * 128 + nl;
    const float* R = rot + n * 9;
    float R00 = R[0], R01 = R[1], R02 = R[2];
    float R10 = R[3], R11 = R[4], R12 = R[5];
    float R20 = R[6], R21 = R[7], R22 = R[8];
    float t0 = trans[n * 3 + 0], t1 = trans[n * 3 + 1], t2 = trans[n * 3 + 2];

    if (role == 0) {
        const float* kr = P + n * PCOLS + K0 + h * 16;
#pragma unroll
        for (int d = 0; d < 16; ++d) kb[d * 128 + nl] = kr[d];
        const float* kp = P + n * PCOLS + KP0 + h * 12;
        float k2 = 0.f;
#pragma unroll
        for (int pt = 0; pt < 4; ++pt) {
            float p0 = kp[pt * 3 + 0], p1 = kp[pt * 3 + 1], p2 = kp[pt * 3 + 2];
            float g0 = R00 * p0 + R01 * p1 + R02 * p2 + t0;
            float g1 = R10 * p0 + R11 * p1 + R12 * p2 + t1;
            float g2 = R20 * p0 + R21 * p1 + R22 * p2 + t2;
            kb[(16 + pt * 3 + 0) * 128 + nl] = g0;
            kb[(16 + pt * 3 + 1) * 128 + nl] = g1;
            kb[(16 + pt * 3 + 2) * 128 + nl] = g2;
            k2 += g0 * g0 + g1 * g1 + g2 * g2;
        }
        kb[28 * 128 + nl] = -CC2 * k2;
    } else {
        const float* qr = P + n * PCOLS + Q0 + h * 16;
#pragma unroll
        for (int d = 0; d < 16; ++d) qb[d * 128 + nl] = qr[d] * ISD;
        const float* qp = P + n * PCOLS + QP0 + h * 12;
        float q2 = 0.f;
#pragma unroll
        for (int pt = 0; pt < 4; ++pt) {
            float p0 = qp[pt * 3 + 0], p1 = qp[pt * 3 + 1], p2 = qp[pt * 3 + 2];
            float g0 = R00 * p0 + R01 * p1 + R02 * p2 + t0;
            float g1 = R10 * p0 + R11 * p1 + R12 * p2 + t1;
            float g2 = R20 * p0 + R21 * p1 + R22 * p2 + t2;
            qb[(16 + pt * 3 + 0) * 128 + nl] = g0 * (2.f * CC2);
            qb[(16 + pt * 3 + 1) * 128 + nl] = g1 * (2.f * CC2);
            qb[(16 + pt * 3 + 2) * 128 + nl] = g2 * (2.f * CC2);
            q2 += g0 * g0 + g1 * g1 + g2 * g2;
        }
        qb[28 * 128 + nl] = 1.0f;
        qcb[nl] = fmaf(-CC2, q2, -4.0f);
        const float* vr = P + n * PCOLS + V0 + h * 16;
#pragma unroll
        for (int d = 0; d < 16; ++d) vb[d * 128 + nl] = vr[d];
        const float* vp = P + n * PCOLS + VP0 + h * 12;
#pragma unroll
        for (int pt = 0; pt < 4; ++pt) {
            float p0 = vp[pt * 3 + 0], p1 = vp[pt * 3 + 1], p2 = vp[pt * 3 + 2];
            vb[(16 + pt * 3 + 0) * 128 + nl] = R00 * p0 + R01 * p1 + R02 * p2 + t0;
            vb[(16 + pt * 3 + 1) * 128 + nl] = R10 * p0 + R11 * p1 + R12 * p2 + t1;
            vb[(16 + pt * 3 + 2) * 128 + nl] = R20 * p0 + R21 * p1 + R22 * p2 + t2;
        }
    }
    __syncthreads();

    for (int u = tid; u < 57 * 32; u += 256) {
        int d = u >> 5, c4 = u & 31;
        float4 v = (d < 29) ? *(float4*)&kb[d * 128 + c4 * 4]
                            : *(float4*)&vb[(d - 29) * 128 + c4 * 4];
        *(float4*)&KVg[(h * KV_ROWS + d) * 1024 + nb * 128 + c4 * 4] = v;
    }
    for (int u = tid; u < 29 * 32; u += 256) {
        int d = u >> 5, c4 = u & 31;
        *(float4*)&Qg[(h * 29 + d) * 1024 + nb * 128 + c4 * 4] = *(float4*)&qb[d * 128 + c4 * 4];
    }
    if (tid < 32) *(float4*)&qcg[h * 1024 + nb * 128 + tid * 4] = *(float4*)&qcb[tid * 4];
}

// ---------- attention as register-tiled GEMM, global_load_lds staging ----------
// grid (16, 12, 4), 256 thr (16 ty x 16 tx). Thread tile: 4 queries x 4 keys.
// Block: 64 queries x 256 keys (4 tiles of 64, double-buffered LDS via DMA).
__global__ __launch_bounds__(256, 3) void k_attn(
    const float* __restrict__ KVg, const float* __restrict__ Qg,
    const float* __restrict__ qcg, float* __restrict__ part)
{
    __shared__ float Qs[29 * 64];
    __shared__ float KV[2][KV_ROWS * 64];
    int tid = threadIdx.x;
    int lane = tid & 63, w = tid >> 6;
    int ty = tid >> 4, tx = tid & 15;
    int i0 = blockIdx.x * 64;
    int h = blockIdx.y;
    int jz0 = blockIdx.z * 256;
    const float* KVh = KVg + h * KV_ROWS * 1024;

    for (int u = tid; u < 29 * 16; u += 256) {
        int d = u >> 4, c4 = u & 15;
        *(float4*)&Qs[d * 64 + c4 * 4] = *(const float4*)&Qg[(h * 29 + d) * 1024 + i0 + c4 * 4];
    }
    float qc[4];
#pragma unroll
    for (int r = 0; r < 4; ++r) qc[r] = qcg[h * 1024 + i0 + ty * 4 + r];

    // wave w issues DMA instr g = w*4+m; each instr stages 1KB = 4 rows of [64].
    int nst = (w < 3) ? 4 : 3;
#define STAGE(T) do { float* buf_ = KV[(T) & 1]; int j0_ = jz0 + (T) * 64;        \
        for (int m_ = 0; m_ < nst; ++m_) {                                        \
            int g_ = w * 4 + m_;                                                  \
            const float* src_ = KVh + (g_ * 4 + (lane >> 4)) * 1024 + j0_ + (lane & 15) * 4; \
            float* dst_ = buf_ + g_ * 256;                                        \
            __builtin_amdgcn_global_load_lds(                                     \
                (const __attribute__((address_space(1))) void*)src_,              \
                (__attribute__((address_space(3))) void*)dst_, 16, 0, 0);         \
        } } while (0)

    STAGE(0);
    __syncthreads();

    float out[4][28] = {};
    float denom[4] = {};

    for (int t = 0; t < 4; ++t) {
        if (t < 3) STAGE(t + 1);
        const float* Kb = KV[t & 1];
        const float* Vb = Kb + 29 * 64;

        float s[4][4] = {};
#pragma unroll
        for (int d = 0; d < 29; ++d) {
            float4 qv = *(const float4*)&Qs[d * 64 + ty * 4];
            float4 kv = *(const float4*)&Kb[d * 64 + tx * 4];
            float qa[4] = {qv.x, qv.y, qv.z, qv.w};
            float ka[4] = {kv.x, kv.y, kv.z, kv.w};
#pragma unroll
            for (int r = 0; r < 4; ++r)
#pragma unroll
                for (int j = 0; j < 4; ++j) s[r][j] = fmaf(qa[r], ka[j], s[r][j]);
        }

        float p[4][4];
#pragma unroll
        for (int r = 0; r < 4; ++r) {
#pragma unroll
            for (int j = 0; j < 4; ++j) {
                p[r][j] = __expf(s[r][j] + qc[r]);
                denom[r] += p[r][j];
            }
        }

#pragma unroll
        for (int d = 0; d < 28; ++d) {
            float4 vv = *(const float4*)&Vb[d * 64 + tx * 4];
            float va[4] = {vv.x, vv.y, vv.z, vv.w};
#pragma unroll
            for (int r = 0; r < 4; ++r) {
                float acc = out[r][d];
#pragma unroll
                for (int j = 0; j < 4; ++j) acc = fmaf(p[r][j], va[j], acc);
                out[r][d] = acc;
            }
        }
        __syncthreads();
    }

    // butterfly reduce across the 16 tx lanes (lane bits 0..3)
#pragma unroll
    for (int m = 1; m <= 8; m <<= 1) {
#pragma unroll
        for (int r = 0; r < 4; ++r) {
#pragma unroll
            for (int d = 0; d < 28; ++d) out[r][d] += __shfl_xor(out[r][d], m, 64);
            denom[r] += __shfl_xor(denom[r], m, 64);
        }
    }
    if (tx == 0) {
#pragma unroll
        for (int r = 0; r < 4; ++r) {
#pragma unroll
            for (int d = 0; d < 28; ++d) Qs[d * 64 + ty * 4 + r] = out[r][d];
            Qs[28 * 64 + ty * 4 + r] = denom[r];
        }
    }
    __syncthreads();
    for (int u = tid; u < 29 * 64; u += 256) {
        part[((blockIdx.z * H_NUM + h) * 29 + (u >> 6)) * N_TOK + i0 + (u & 63)] = Qs[u];
    }
}

// ---------- combine 4 partials, normalize, point-norm epilogue ----------
__global__ __launch_bounds__(256) void k_comb(
    const float* __restrict__ part, const float* __restrict__ rot,
    const float* __restrict__ trans, float* __restrict__ att)
{
    int t = blockIdx.x * 256 + threadIdx.x;
    int h = t >> 10, i = t & 1023;
    float v[29];
#pragma unroll
    for (int c = 0; c < 29; ++c) {
        float s = 0.f;
#pragma unroll
        for (int z = 0; z < NZ; ++z)
            s += part[((z * H_NUM + h) * 29 + c) * N_TOK + i];
        v[c] = s;
    }
    float inv = 1.f / v[28];
    float* arow = att + i * ATT_W;
#pragma unroll
    for (int d = 0; d < 16; ++d) arow[h * 16 + d] = v[d] * inv;
    float t0 = trans[i * 3 + 0], t1 = trans[i * 3 + 1], t2v = trans[i * 3 + 2];
    const float* R = rot + i * 9;
#pragma unroll
    for (int p = 0; p < 4; ++p) {
        float c0 = v[16 + p * 3 + 0] * inv - t0;
        float c1 = v[16 + p * 3 + 1] * inv - t1;
        float c2 = v[16 + p * 3 + 2] * inv - t2v;
        float l0 = R[0] * c0 + R[3] * c1 + R[6] * c2;
        float l1 = R[1] * c0 + R[4] * c1 + R[7] * c2;
        float l2 = R[2] * c0 + R[5] * c1 + R[8] * c2;
        arow[192 + h * 4 + p] = sqrtf(l0 * l0 + l1 * l1 + l2 * l2);
    }
}

// ---------- out GEMM: out[1024][384] = att[1024][240] @ Wout[240][384] + bout ----------
__global__ __launch_bounds__(256) void k_out(
    const float* __restrict__ att, const float* __restrict__ Wout,
    const float* __restrict__ bout, float* __restrict__ out)
{
    __shared__ float xs[64][17];
    __shared__ float wsh[16][64];
    int tid = threadIdx.x;
    int i0 = blockIdx.x * 64, c0 = blockIdx.y * 64;
    int lr = tid >> 2, lk = (tid & 3) * 4;
    int wr = tid >> 4, wc = (tid & 15) * 4;
    int ty = tid >> 4, tx = tid & 15;

    float4 xa = *(const float4*)(att + (i0 + lr) * ATT_W + lk);
    float4 wa = *(const float4*)(Wout + wr * C_DIM + c0 + wc);
    float acc[4][4] = {};

    for (int it = 0; it < 15; ++it) {
        xs[lr][lk + 0] = xa.x; xs[lr][lk + 1] = xa.y;
        xs[lr][lk + 2] = xa.z; xs[lr][lk + 3] = xa.w;
        *(float4*)&wsh[wr][wc] = wa;
        __syncthreads();
        if (it < 14) {
            xa = *(const float4*)(att + (i0 + lr) * ATT_W + (it + 1) * 16 + lk);
            wa = *(const float4*)(Wout + ((it + 1) * 16 + wr) * C_DIM + c0 + wc);
        }
#pragma unroll
        for (int kk = 0; kk < 16; ++kk) {
            float4 b = *(float4*)&wsh[kk][tx * 4];
            float a0 = xs[ty * 4 + 0][kk];
            float a1 = xs[ty * 4 + 1][kk];
            float a2 = xs[ty * 4 + 2][kk];
            float a3 = xs[ty * 4 + 3][kk];
            acc[0][0] = fmaf(a0, b.x, acc[0][0]); acc[0][1] = fmaf(a0, b.y, acc[0][1]);
            acc[0][2] = fmaf(a0, b.z, acc[0][2]); acc[0][3] = fmaf(a0, b.w, acc[0][3]);
            acc[1][0] = fmaf(a1, b.x, acc[1][0]); acc[1][1] = fmaf(a1, b.y, acc[1][1]);
            acc[1][2] = fmaf(a1, b.z, acc[1][2]); acc[1][3] = fmaf(a1, b.w, acc[1][3]);
            acc[2][0] = fmaf(a2, b.x, acc[2][0]); acc[2][1] = fmaf(a2, b.y, acc[2][1]);
            acc[2][2] = fmaf(a2, b.z, acc[2][2]); acc[2][3] = fmaf(a2, b.w, acc[2][3]);
            acc[3][0] = fmaf(a3, b.x, acc[3][0]); acc[3][1] = fmaf(a3, b.y, acc[3][1]);
            acc[3][2] = fmaf(a3, b.z, acc[3][2]); acc[3][3] = fmaf(a3, b.w, acc[3][3]);
        }
        __syncthreads();
    }
    float4 bb = *(const float4*)(bout + c0 + tx * 4);
#pragma unroll
    for (int r = 0; r < 4; ++r) {
        *(float4*)(out + (i0 + ty * 4 + r) * C_DIM + c0 + tx * 4) =
            make_float4(acc[r][0] + bb.x, acc[r][1] + bb.y, acc[r][2] + bb.z, acc[r][3] + bb.w);
    }
}

extern "C" void kernel_launch(void* const* d_in, const int* in_sizes, int n_in,
                              void* d_out, int out_size, void* d_ws, size_t ws_size,
                              hipStream_t stream) {
    const float* x     = (const float*)d_in[0];
    const float* rot   = (const float*)d_in[1];
    const float* trans = (const float*)d_in[2];
    const float* Wq    = (const float*)d_in[3];
    const float* Wk    = (const float*)d_in[4];
    const float* Wv    = (const float*)d_in[5];
    const float* Wqp   = (const float*)d_in[6];
    const float* Wkp   = (const float*)d_in[7];
    const float* Wvp   = (const float*)d_in[8];
    const float* Wout  = (const float*)d_in[9];
    const float* bout  = (const float*)d_in[10];
    float* out = (float*)d_out;

    float* ws = (float*)d_ws;
    float* Wall = ws;                            // 384*1024
    float* P    = Wall + C_DIM * PCOLS;          // 1024*1024
    float* KVg  = P    + N_TOK * PCOLS;          // 12*60*1024
    float* Qg   = KVg  + H_NUM * KV_ROWS * 1024; // 12*29*1024
    float* qcg  = Qg   + H_NUM * 29 * 1024;      // 12*1024
    float* part = ws;                            // alias Wall+P: NZ*12*29*1024 = 1.43M <= 1.44M
    float* att  = Qg;                            // alias Qg (dead after k_attn)

    k_pack<<<384, 256, 0, stream>>>(Wq, Wk, Wv, Wqp, Wkp, Wvp, Wall);
    k_proj<<<dim3(16, 16), 256, 0, stream>>>(x, Wall, P);
    k_prep<<<dim3(8, 12), 256, 0, stream>>>(P, rot, trans, KVg, Qg, qcg);
    k_attn<<<dim3(16, 12, NZ), 256, 0, stream>>>(KVg, Qg, qcg, part);
    k_comb<<<48, 256, 0, stream>>>(part, rot, trans, att);
    k_out<<<dim3(16, 6), 256, 0, stream>>>(att, Wout, bout, out);
}

// Round 10
// 94.052 us; speedup vs baseline: 3.5371x; 1.1612x over previous
//
#include <hip/hip_runtime.h>
#include <math.h>

#define N_TOK 1024
#define C_DIM 384
#define H_NUM 12
#define PCOLS 1024
#define Q0 0
#define K0 192
#define V0 384
#define QP0 576
#define KP0 720
#define VP0 864
#define ATT_W 240
#define COEF 0.11785113019775792f   // 0.5*sqrt(2/36)
#define ISD 0.25f
#define CC2 (COEF * ISD)            // 0.029462...
#define KV_ROWS 60                  // 29 K' + 28 V' + 3 pad (DMA tiles by 4 rows)
#define NZ 4

// ---------- pack 6 weight mats into Wall[384][1024] (cols 1008..1023 zero) ----------
__global__ __launch_bounds__(256) void k_pack(
    const float* __restrict__ Wq, const float* __restrict__ Wk, const float* __restrict__ Wv,
    const float* __restrict__ Wqp, const float* __restrict__ Wkp, const float* __restrict__ Wvp,
    float* __restrict__ Wall)
{
    int t = blockIdx.x * 256 + threadIdx.x;
    int k = t >> 8;
    int col = (t & 255) * 4;
    float4 v;
    if (col < 192)       v = *(const float4*)(Wq  + k * 192 + col);
    else if (col < 384)  v = *(const float4*)(Wk  + k * 192 + col - 192);
    else if (col < 576)  v = *(const float4*)(Wv  + k * 192 + col - 384);
    else if (col < 720)  v = *(const float4*)(Wqp + k * 144 + col - 576);
    else if (col < 864)  v = *(const float4*)(Wkp + k * 144 + col - 720);
    else if (col < 1008) v = *(const float4*)(Wvp + k * 144 + col - 864);
    else                 v = make_float4(0.f, 0.f, 0.f, 0.f);
    *(float4*)(Wall + k * PCOLS + col) = v;
}

// ---------- proj GEMM: P[1024][1024] = x[1024][384] @ Wall[384][1024] ----------
__global__ __launch_bounds__(256) void k_proj(
    const float* __restrict__ x, const float* __restrict__ Wall, float* __restrict__ P)
{
    __shared__ float xs[64][17];
    __shared__ float wsh[16][64];
    int tid = threadIdx.x;
    int i0 = blockIdx.x * 64, c0 = blockIdx.y * 64;
    int lr = tid >> 2, lk = (tid & 3) * 4;
    int wr = tid >> 4, wc = (tid & 15) * 4;
    int ty = tid >> 4, tx = tid & 15;

    float4 xa = *(const float4*)(x + (i0 + lr) * C_DIM + lk);
    float4 wa = *(const float4*)(Wall + wr * PCOLS + c0 + wc);
    float acc[4][4] = {};

    for (int it = 0; it < 24; ++it) {
        xs[lr][lk + 0] = xa.x; xs[lr][lk + 1] = xa.y;
        xs[lr][lk + 2] = xa.z; xs[lr][lk + 3] = xa.w;
        *(float4*)&wsh[wr][wc] = wa;
        __syncthreads();
        if (it < 23) {
            xa = *(const float4*)(x + (i0 + lr) * C_DIM + (it + 1) * 16 + lk);
            wa = *(const float4*)(Wall + ((it + 1) * 16 + wr) * PCOLS + c0 + wc);
        }
#pragma unroll
        for (int kk = 0; kk < 16; ++kk) {
            float4 b = *(float4*)&wsh[kk][tx * 4];
            float a0 = xs[ty * 4 + 0][kk];
            float a1 = xs[ty * 4 + 1][kk];
            float a2 = xs[ty * 4 + 2][kk];
            float a3 = xs[ty * 4 + 3][kk];
            acc[0][0] = fmaf(a0, b.x, acc[0][0]); acc[0][1] = fmaf(a0, b.y, acc[0][1]);
            acc[0][2] = fmaf(a0, b.z, acc[0][2]); acc[0][3] = fmaf(a0, b.w, acc[0][3]);
            acc[1][0] = fmaf(a1, b.x, acc[1][0]); acc[1][1] = fmaf(a1, b.y, acc[1][1]);
            acc[1][2] = fmaf(a1, b.z, acc[1][2]); acc[1][3] = fmaf(a1, b.w, acc[1][3]);
            acc[2][0] = fmaf(a2, b.x, acc[2][0]); acc[2][1] = fmaf(a2, b.y, acc[2][1]);
            acc[2][2] = fmaf(a2, b.z, acc[2][2]); acc[2][3] = fmaf(a2, b.w, acc[2][3]);
            acc[3][0] = fmaf(a3, b.x, acc[3][0]); acc[3][1] = fmaf(a3, b.y, acc[3][1]);
            acc[3][2] = fmaf(a3, b.z, acc[3][2]); acc[3][3] = fmaf(a3, b.w, acc[3][3]);
        }
        __syncthreads();
    }
#pragma unroll
    for (int r = 0; r < 4; ++r) {
        *(float4*)(P + (i0 + ty * 4 + r) * PCOLS + c0 + tx * 4) =
            make_float4(acc[r][0], acc[r][1], acc[r][2], acc[r][3]);
    }
}

// ---------- prep: build d-major Q'[h][29][1024], KV'[h][60][1024], qc[h][1024] ----------
__global__ __launch_bounds__(256) void k_prep(
    const float* __restrict__ P, const float* __restrict__ rot, const float* __restrict__ trans,
    float* __restrict__ KVg, float* __restrict__ Qg, float* __restrict__ qcg)
{
    __shared__ float kb[29 * 128];
    __shared__ float qb[29 * 128];
    __shared__ float vb[28 * 128];
    __shared__ float qcb[128];
    int h = blockIdx.y, nb = blockIdx.x;
    int tid = threadIdx.x;
    int nl = tid & 127, role = tid >> 7;
    int n = nb * 128 + nl;
    const float* R = rot + n * 9;
    float R00 = R[0], R01 = R[1], R02 = R[2];
    float R10 = R[3], R11 = R[4], R12 = R[5];
    float R20 = R[6], R21 = R[7], R22 = R[8];
    float t0 = trans[n * 3 + 0], t1 = trans[n * 3 + 1], t2 = trans[n * 3 + 2];

    if (role == 0) {
        const float* kr = P + n * PCOLS + K0 + h * 16;
#pragma unroll
        for (int d = 0; d < 16; ++d) kb[d * 128 + nl] = kr[d];
        const float* kp = P + n * PCOLS + KP0 + h * 12;
        float k2 = 0.f;
#pragma unroll
        for (int pt = 0; pt < 4; ++pt) {
            float p0 = kp[pt * 3 + 0], p1 = kp[pt * 3 + 1], p2 = kp[pt * 3 + 2];
            float g0 = R00 * p0 + R01 * p1 + R02 * p2 + t0;
            float g1 = R10 * p0 + R11 * p1 + R12 * p2 + t1;
            float g2 = R20 * p0 + R21 * p1 + R22 * p2 + t2;
            kb[(16 + pt * 3 + 0) * 128 + nl] = g0;
            kb[(16 + pt * 3 + 1) * 128 + nl] = g1;
            kb[(16 + pt * 3 + 2) * 128 + nl] = g2;
            k2 += g0 * g0 + g1 * g1 + g2 * g2;
        }
        kb[28 * 128 + nl] = -CC2 * k2;
    } else {
        const float* qr = P + n * PCOLS + Q0 + h * 16;
#pragma unroll
        for (int d = 0; d < 16; ++d) qb[d * 128 + nl] = qr[d] * ISD;
        const float* qp = P + n * PCOLS + QP0 + h * 12;
        float q2 = 0.f;
#pragma unroll
        for (int pt = 0; pt < 4; ++pt) {
            float p0 = qp[pt * 3 + 0], p1 = qp[pt * 3 + 1], p2 = qp[pt * 3 + 2];
            float g0 = R00 * p0 + R01 * p1 + R02 * p2 + t0;
            float g1 = R10 * p0 + R11 * p1 + R12 * p2 + t1;
            float g2 = R20 * p0 + R21 * p1 + R22 * p2 + t2;
            qb[(16 + pt * 3 + 0) * 128 + nl] = g0 * (2.f * CC2);
            qb[(16 + pt * 3 + 1) * 128 + nl] = g1 * (2.f * CC2);
            qb[(16 + pt * 3 + 2) * 128 + nl] = g2 * (2.f * CC2);
            q2 += g0 * g0 + g1 * g1 + g2 * g2;
        }
        qb[28 * 128 + nl] = 1.0f;
        qcb[nl] = fmaf(-CC2, q2, -4.0f);
        const float* vr = P + n * PCOLS + V0 + h * 16;
#pragma unroll
        for (int d = 0; d < 16; ++d) vb[d * 128 + nl] = vr[d];
        const float* vp = P + n * PCOLS + VP0 + h * 12;
#pragma unroll
        for (int pt = 0; pt < 4; ++pt) {
            float p0 = vp[pt * 3 + 0], p1 = vp[pt * 3 + 1], p2 = vp[pt * 3 + 2];
            vb[(16 + pt * 3 + 0) * 128 + nl] = R00 * p0 + R01 * p1 + R02 * p2 + t0;
            vb[(16 + pt * 3 + 1) * 128 + nl] = R10 * p0 + R11 * p1 + R12 * p2 + t1;
            vb[(16 + pt * 3 + 2) * 128 + nl] = R20 * p0 + R21 * p1 + R22 * p2 + t2;
        }
    }
    __syncthreads();

    for (int u = tid; u < 57 * 32; u += 256) {
        int d = u >> 5, c4 = u & 31;
        float4 v = (d < 29) ? *(float4*)&kb[d * 128 + c4 * 4]
                            : *(float4*)&vb[(d - 29) * 128 + c4 * 4];
        *(float4*)&KVg[(h * KV_ROWS + d) * 1024 + nb * 128 + c4 * 4] = v;
    }
    for (int u = tid; u < 29 * 32; u += 256) {
        int d = u >> 5, c4 = u & 31;
        *(float4*)&Qg[(h * 29 + d) * 1024 + nb * 128 + c4 * 4] = *(float4*)&qb[d * 128 + c4 * 4];
    }
    if (tid < 32) *(float4*)&qcg[h * 1024 + nb * 128 + tid * 4] = *(float4*)&qcb[tid * 4];
}

// ---------- attention as register-tiled GEMM, global_load_lds staging ----------
// 1-D grid 768, decoded XCD-colocating: blocks sharing one (h,z) KV tile land on one XCD.
// 256 thr: ty = tid>>3 (32 q-groups x 2), tx = tid&7 (8 key-groups x 8). Thread: 2q x 8k.
__global__ __launch_bounds__(256, 3) void k_attn(
    const float* __restrict__ KVg, const float* __restrict__ Qg,
    const float* __restrict__ qcg, float* __restrict__ part)
{
    __shared__ float Qs[29 * 64];
    __shared__ float KV[2][KV_ROWS * 64];
    int tid = threadIdx.x;
    int lane = tid & 63, w = tid >> 6;
    int ty = tid >> 3, tx = tid & 7;

    int bid = blockIdx.x;
    int xcd = bid & 7, slot = bid >> 3;
    int pair = xcd * 6 + (slot >> 4);     // 0..47
    int bx = slot & 15;
    int h = pair % H_NUM;
    int z = pair / H_NUM;

    int i0 = bx * 64;
    int jz0 = z * 256;
    const float* KVh = KVg + h * KV_ROWS * 1024;

    for (int u = tid; u < 29 * 16; u += 256) {
        int d = u >> 4, c4 = u & 15;
        *(float4*)&Qs[d * 64 + c4 * 4] = *(const float4*)&Qg[(h * 29 + d) * 1024 + i0 + c4 * 4];
    }
    float qc[2];
#pragma unroll
    for (int r = 0; r < 2; ++r) qc[r] = qcg[h * 1024 + i0 + ty * 2 + r];

    // wave w issues DMA instr g = w*4+m; each instr stages 1KB = 4 rows of [64].
    int nst = (w < 3) ? 4 : 3;
#define STAGE(T) do { float* buf_ = KV[(T) & 1]; int j0_ = jz0 + (T) * 64;        \
        for (int m_ = 0; m_ < nst; ++m_) {                                        \
            int g_ = w * 4 + m_;                                                  \
            const float* src_ = KVh + (g_ * 4 + (lane >> 4)) * 1024 + j0_ + (lane & 15) * 4; \
            float* dst_ = buf_ + g_ * 256;                                        \
            __builtin_amdgcn_global_load_lds(                                     \
                (const __attribute__((address_space(1))) void*)src_,              \
                (__attribute__((address_space(3))) void*)dst_, 16, 0, 0);         \
        } } while (0)

    STAGE(0);
    __syncthreads();

    float out[2][28] = {};
    float denom[2] = {};

    for (int t = 0; t < 4; ++t) {
        if (t < 3) STAGE(t + 1);
        const float* Kb = KV[t & 1];
        const float* Vb = Kb + 29 * 64;

        float s[2][8] = {};
#pragma unroll
        for (int d = 0; d < 29; ++d) {
            float2 qv = *(const float2*)&Qs[d * 64 + ty * 2];
            float4 k0 = *(const float4*)&Kb[d * 64 + tx * 8];
            float4 k1 = *(const float4*)&Kb[d * 64 + tx * 8 + 4];
            float ka[8] = {k0.x, k0.y, k0.z, k0.w, k1.x, k1.y, k1.z, k1.w};
#pragma unroll
            for (int j = 0; j < 8; ++j) {
                s[0][j] = fmaf(qv.x, ka[j], s[0][j]);
                s[1][j] = fmaf(qv.y, ka[j], s[1][j]);
            }
        }

        float p[2][8];
#pragma unroll
        for (int r = 0; r < 2; ++r) {
#pragma unroll
            for (int j = 0; j < 8; ++j) {
                p[r][j] = __expf(s[r][j] + qc[r]);
                denom[r] += p[r][j];
            }
        }

#pragma unroll
        for (int d = 0; d < 28; ++d) {
            float4 v0 = *(const float4*)&Vb[d * 64 + tx * 8];
            float4 v1 = *(const float4*)&Vb[d * 64 + tx * 8 + 4];
            float va[8] = {v0.x, v0.y, v0.z, v0.w, v1.x, v1.y, v1.z, v1.w};
#pragma unroll
            for (int r = 0; r < 2; ++r) {
                float acc = out[r][d];
#pragma unroll
                for (int j = 0; j < 8; ++j) acc = fmaf(p[r][j], va[j], acc);
                out[r][d] = acc;
            }
        }
        __syncthreads();
    }

    // butterfly reduce across the 8 tx lanes (lane bits 0..2)
#pragma unroll
    for (int m = 1; m <= 4; m <<= 1) {
#pragma unroll
        for (int r = 0; r < 2; ++r) {
#pragma unroll
            for (int d = 0; d < 28; ++d) out[r][d] += __shfl_xor(out[r][d], m, 64);
            denom[r] += __shfl_xor(denom[r], m, 64);
        }
    }
    if (tx == 0) {
#pragma unroll
        for (int r = 0; r < 2; ++r) {
#pragma unroll
            for (int d = 0; d < 28; ++d) Qs[d * 64 + ty * 2 + r] = out[r][d];
            Qs[28 * 64 + ty * 2 + r] = denom[r];
        }
    }
    __syncthreads();
    for (int u = tid; u < 29 * 64; u += 256) {
        part[((z * H_NUM + h) * 29 + (u >> 6)) * N_TOK + i0 + (u & 63)] = Qs[u];
    }
}

// ---------- combine 4 partials, normalize, point-norm epilogue ----------
__global__ __launch_bounds__(256) void k_comb(
    const float* __restrict__ part, const float* __restrict__ rot,
    const float* __restrict__ trans, float* __restrict__ att)
{
    int t = blockIdx.x * 256 + threadIdx.x;
    int h = t >> 10, i = t & 1023;
    float v[29];
#pragma unroll
    for (int c = 0; c < 29; ++c) {
        float s = 0.f;
#pragma unroll
        for (int z = 0; z < NZ; ++z)
            s += part[((z * H_NUM + h) * 29 + c) * N_TOK + i];
        v[c] = s;
    }
    float inv = 1.f / v[28];
    float* arow = att + i * ATT_W;
#pragma unroll
    for (int d = 0; d < 16; ++d) arow[h * 16 + d] = v[d] * inv;
    float t0 = trans[i * 3 + 0], t1 = trans[i * 3 + 1], t2v = trans[i * 3 + 2];
    const float* R = rot + i * 9;
#pragma unroll
    for (int p = 0; p < 4; ++p) {
        float c0 = v[16 + p * 3 + 0] * inv - t0;
        float c1 = v[16 + p * 3 + 1] * inv - t1;
        float c2 = v[16 + p * 3 + 2] * inv - t2v;
        float l0 = R[0] * c0 + R[3] * c1 + R[6] * c2;
        float l1 = R[1] * c0 + R[4] * c1 + R[7] * c2;
        float l2 = R[2] * c0 + R[5] * c1 + R[8] * c2;
        arow[192 + h * 4 + p] = sqrtf(l0 * l0 + l1 * l1 + l2 * l2);
    }
}

// ---------- out GEMM: out[1024][384] = att[1024][240] @ Wout[240][384] + bout ----------
__global__ __launch_bounds__(256) void k_out(
    const float* __restrict__ att, const float* __restrict__ Wout,
    const float* __restrict__ bout, float* __restrict__ out)
{
    __shared__ float xs[64][17];
    __shared__ float wsh[16][64];
    int tid = threadIdx.x;
    int i0 = blockIdx.x * 64, c0 = blockIdx.y * 64;
    int lr = tid >> 2, lk = (tid & 3) * 4;
    int wr = tid >> 4, wc = (tid & 15) * 4;
    int ty = tid >> 4, tx = tid & 15;

    float4 xa = *(const float4*)(att + (i0 + lr) * ATT_W + lk);
    float4 wa = *(const float4*)(Wout + wr * C_DIM + c0 + wc);
    float acc[4][4] = {};

    for (int it = 0; it < 15; ++it) {
        xs[lr][lk + 0] = xa.x; xs[lr][lk + 1] = xa.y;
        xs[lr][lk + 2] = xa.z; xs[lr][lk + 3] = xa.w;
        *(float4*)&wsh[wr][wc] = wa;
        __syncthreads();
        if (it < 14) {
            xa = *(const float4*)(att + (i0 + lr) * ATT_W + (it + 1) * 16 + lk);
            wa = *(const float4*)(Wout + ((it + 1) * 16 + wr) * C_DIM + c0 + wc);
        }
#pragma unroll
        for (int kk = 0; kk < 16; ++kk) {
            float4 b = *(float4*)&wsh[kk][tx * 4];
            float a0 = xs[ty * 4 + 0][kk];
            float a1 = xs[ty * 4 + 1][kk];
            float a2 = xs[ty * 4 + 2][kk];
            float a3 = xs[ty * 4 + 3][kk];
            acc[0][0] = fmaf(a0, b.x, acc[0][0]); acc[0][1] = fmaf(a0, b.y, acc[0][1]);
            acc[0][2] = fmaf(a0, b.z, acc[0][2]); acc[0][3] = fmaf(a0, b.w, acc[0][3]);
            acc[1][0] = fmaf(a1, b.x, acc[1][0]); acc[1][1] = fmaf(a1, b.y, acc[1][1]);
            acc[1][2] = fmaf(a1, b.z, acc[1][2]); acc[1][3] = fmaf(a1, b.w, acc[1][3]);
            acc[2][0] = fmaf(a2, b.x, acc[2][0]); acc[2][1] = fmaf(a2, b.y, acc[2][1]);
            acc[2][2] = fmaf(a2, b.z, acc[2][2]); acc[2][3] = fmaf(a2, b.w, acc[2][3]);
            acc[3][0] = fmaf(a3, b.x, acc[3][0]); acc[3][1] = fmaf(a3, b.y, acc[3][1]);
            acc[3][2] = fmaf(a3, b.z, acc[3][2]); acc[3][3] = fmaf(a3, b.w, acc[3][3]);
        }
        __syncthreads();
    }
    float4 bb = *(const float4*)(bout + c0 + tx * 4);
#pragma unroll
    for (int r = 0; r < 4; ++r) {
        *(float4*)(out + (i0 + ty * 4 + r) * C_DIM + c0 + tx * 4) =
            make_float4(acc[r][0] + bb.x, acc[r][1] + bb.y, acc[r][2] + bb.z, acc[r][3] + bb.w);
    }
}

extern "C" void kernel_launch(void* const* d_in, const int* in_sizes, int n_in,
                              void* d_out, int out_size, void* d_ws, size_t ws_size,
                              hipStream_t stream) {
    const float* x     = (const float*)d_in[0];
    const float* rot   = (const float*)d_in[1];
    const float* trans = (const float*)d_in[2];
    const float* Wq    = (const float*)d_in[3];
    const float* Wk    = (const float*)d_in[4];
    const float* Wv    = (const float*)d_in[5];
    const float* Wqp   = (const float*)d_in[6];
    const float* Wkp   = (const float*)d_in[7];
    const float* Wvp   = (const float*)d_in[8];
    const float* Wout  = (const float*)d_in[9];
    const float* bout  = (const float*)d_in[10];
    float* out = (float*)d_out;

    float* ws = (float*)d_ws;
    float* Wall = ws;                            // 384*1024
    float* P    = Wall + C_DIM * PCOLS;          // 1024*1024
    float* KVg  = P    + N_TOK * PCOLS;          // 12*60*1024
    float* Qg   = KVg  + H_NUM * KV_ROWS * 1024; // 12*29*1024
    float* qcg  = Qg   + H_NUM * 29 * 1024;      // 12*1024
    float* part = ws;                            // alias Wall+P: NZ*12*29*1024 = 1.43M <= 1.44M
    float* att  = Qg;                            // alias Qg (dead after k_attn)

    k_pack<<<384, 256, 0, stream>>>(Wq, Wk, Wv, Wqp, Wkp, Wvp, Wall);
    k_proj<<<dim3(16, 16), 256, 0, stream>>>(x, Wall, P);
    k_prep<<<dim3(8, 12), 256, 0, stream>>>(P, rot, trans, KVg, Qg, qcg);
    k_attn<<<768, 256, 0, stream>>>(KVg, Qg, qcg, part);
    k_comb<<<48, 256, 0, stream>>>(part, rot, trans, att);
    k_out<<<dim3(16, 6), 256, 0, stream>>>(att, Wout, bout, out);
}